// Round 4
// baseline (70.493 us; speedup 1.0000x reference)
//
#include <hip/hip_runtime.h>
#include <hip/hip_bf16.h>
#include <math.h>

// Problem constants (B,U,D) = (4096, 256, 128)
#define BN 4096
#define UN 256
#define DN 128
#define MROW 16        // batch rows per block (one M=16 MFMA tile)
#define BLOCK 1024     // 16 waves: wave w owns u-tile w (u = w*16 .. w*16+15)
#define LSTRIDE 260    // logits row stride (floats); +4 pad -> 2-way banks (free)

typedef __attribute__((ext_vector_type(8))) short short8x;   // 8 bf16
typedef __attribute__((ext_vector_type(4))) float float4x;   // MFMA C/D

__device__ inline uint pack2bf(float a, float b) {
    __hip_bfloat16 ha = __float2bfloat16(a);
    __hip_bfloat16 hb = __float2bfloat16(b);
    return (uint)(*(ushort*)&ha) | ((uint)(*(ushort*)&hb) << 16);
}

__global__ __launch_bounds__(BLOCK, 4) void fused_kernel(
    const float* __restrict__ x,     // [B, D]
    const float* __restrict__ W,     // [U, D]
    const float* __restrict__ bias,  // [U, D]
    float* __restrict__ out)         // [B, U]
{
    __shared__ __align__(16) float logits[MROW][LSTRIDE];   // ~16.6 KB

    const int t    = threadIdx.x;
    const int lane = t & 63;
    const int wave = t >> 6;          // u-tile 0..15
    const int m16  = lane & 15;       // A row / B row (=C col) within tile
    const int q    = lane >> 4;       // quad: k-chunk q*8..q*8+7 within each 32
    const int b0   = blockIdx.x * MROW;
    const int u    = wave * 16 + m16;

    // ---- x A-fragments from global (L1-hot across the 16 waves) + exact nv2
    short8x afrag[4];
    float sq = 0.f;
    {
        const float* xr = x + (size_t)(b0 + m16) * DN + q * 8;
        #pragma unroll
        for (int ks = 0; ks < 4; ++ks) {
            const float4 a = *(const float4*)(xr + ks * 32);
            const float4 b = *(const float4*)(xr + ks * 32 + 4);
            sq = fmaf(a.x, a.x, sq); sq = fmaf(a.y, a.y, sq);
            sq = fmaf(a.z, a.z, sq); sq = fmaf(a.w, a.w, sq);
            sq = fmaf(b.x, b.x, sq); sq = fmaf(b.y, b.y, sq);
            sq = fmaf(b.z, b.z, sq); sq = fmaf(b.w, b.w, sq);
            uint4 p;
            p.x = pack2bf(a.x, a.y);  p.y = pack2bf(a.z, a.w);
            p.z = pack2bf(b.x, b.y);  p.w = pack2bf(b.z, b.w);
            afrag[ks] = *(short8x*)&p;
        }
    }
    sq += __shfl_xor(sq, 16);
    sq += __shfl_xor(sq, 32);        // nv2 of row m16, in every lane

    // ---- W/bias B-fragments (L2-hot) + exact per-u scalars, all in-register
    short8x wfrag[4], bfrag[4];
    float nb2 = 0.f, bw = 0.f, wn2 = 0.f;
    {
        const float* wr = W    + (size_t)u * DN + q * 8;
        const float* br = bias + (size_t)u * DN + q * 8;
        #pragma unroll
        for (int ks = 0; ks < 4; ++ks) {
            const float4 w0 = *(const float4*)(wr + ks * 32);
            const float4 w1 = *(const float4*)(wr + ks * 32 + 4);
            const float4 c0 = *(const float4*)(br + ks * 32);
            const float4 c1 = *(const float4*)(br + ks * 32 + 4);
            nb2 = fmaf(c0.x,c0.x, fmaf(c0.y,c0.y, fmaf(c0.z,c0.z, fmaf(c0.w,c0.w,
                  fmaf(c1.x,c1.x, fmaf(c1.y,c1.y, fmaf(c1.z,c1.z, fmaf(c1.w,c1.w, nb2))))))));
            bw  = fmaf(c0.x,w0.x, fmaf(c0.y,w0.y, fmaf(c0.z,w0.z, fmaf(c0.w,w0.w,
                  fmaf(c1.x,w1.x, fmaf(c1.y,w1.y, fmaf(c1.z,w1.z, fmaf(c1.w,w1.w, bw))))))));
            wn2 = fmaf(w0.x,w0.x, fmaf(w0.y,w0.y, fmaf(w0.z,w0.z, fmaf(w0.w,w0.w,
                  fmaf(w1.x,w1.x, fmaf(w1.y,w1.y, fmaf(w1.z,w1.z, fmaf(w1.w,w1.w, wn2))))))));
            uint4 pw, pb;
            pw.x = pack2bf(w0.x, w0.y);  pw.y = pack2bf(w0.z, w0.w);
            pw.z = pack2bf(w1.x, w1.y);  pw.w = pack2bf(w1.z, w1.w);
            pb.x = pack2bf(c0.x, c0.y);  pb.y = pack2bf(c0.z, c0.w);
            pb.z = pack2bf(c1.x, c1.y);  pb.w = pack2bf(c1.z, c1.w);
            wfrag[ks] = *(short8x*)&pw;
            bfrag[ks] = *(short8x*)&pb;
        }
    }
    nb2 += __shfl_xor(nb2, 16);  nb2 += __shfl_xor(nb2, 32);
    bw  += __shfl_xor(bw , 16);  bw  += __shfl_xor(bw , 32);
    wn2 += __shfl_xor(wn2, 16);  wn2 += __shfl_xor(wn2, 32);
    // lane now holds exact (nb2,bw,wn2) for u = wave*16 + m16 == its C column

    // ---- MFMA: D[m][u], C layout col=m16, row=q*4+reg
    float4x accW = {0.f, 0.f, 0.f, 0.f};
    float4x accB = {0.f, 0.f, 0.f, 0.f};
    #pragma unroll
    for (int ks = 0; ks < 4; ++ks) {
        accW = __builtin_amdgcn_mfma_f32_16x16x32_bf16(afrag[ks], wfrag[ks], accW, 0, 0, 0);
        accB = __builtin_amdgcn_mfma_f32_16x16x32_bf16(afrag[ks], bfrag[ks], accB, 0, 0, 0);
    }

    // ---- epilogue: 4 logits per lane
    const float one_m  = 1.0f - nb2;
    const float a_norm = fabsf(one_m) * sqrtf(wn2);
    const float scale  = (2.0f / one_m) * a_norm;
    #pragma unroll
    for (int rg = 0; rg < 4; ++rg) {
        const int   mr   = q * 4 + rg;
        const float nv2  = __shfl(sq, mr);   // lane mr holds nv2 of row mr
        const float dot1 = accW[rg];
        const float xy   = -accB[rg];
        const float dd   = 1.0f + 2.0f * xy + nb2 * nv2;
        const float inv_dd = __builtin_amdgcn_rcpf(dd);
        const float alpha  = (1.0f + 2.0f * xy + nv2) * inv_dd;
        const float beta   = one_m * inv_dd;
        const float num = 2.0f * one_m * (beta * dot1 - alpha * bw);
        const float mm  = alpha * alpha * nb2 + 2.0f * alpha * beta * xy
                        + beta * beta * nv2;
        const float den = (1.0f - mm) * a_norm;
        const float z   = num * __builtin_amdgcn_rcpf(den);
        const float s   = sqrtf(fmaf(z, z, 1.0f));
        logits[mr][u] = scale * copysignf(__logf(fabsf(z) + s), z);
    }
    __syncthreads();

    // ---- softmax: wave w handles row w (16 waves == 16 rows), float4 I/O
    {
        const int r = wave;
        const float4 v = *(const float4*)&logits[r][lane * 4];
        float mx = fmaxf(fmaxf(v.x, v.y), fmaxf(v.z, v.w));
        #pragma unroll
        for (int off = 32; off; off >>= 1) mx = fmaxf(mx, __shfl_xor(mx, off));
        float4 e;
        e.x = __expf(v.x - mx);  e.y = __expf(v.y - mx);
        e.z = __expf(v.z - mx);  e.w = __expf(v.w - mx);
        float s = e.x + e.y + e.z + e.w;
        #pragma unroll
        for (int off = 32; off; off >>= 1) s += __shfl_xor(s, off);
        const float inv = __builtin_amdgcn_rcpf(s);
        e.x *= inv;  e.y *= inv;  e.z *= inv;  e.w *= inv;
        ((float4*)(out + (size_t)(b0 + r) * UN))[lane] = e;
    }
}

extern "C" void kernel_launch(void* const* d_in, const int* in_sizes, int n_in,
                              void* d_out, int out_size, void* d_ws, size_t ws_size,
                              hipStream_t stream) {
    const float* x    = (const float*)d_in[0];
    const float* W    = (const float*)d_in[1];
    const float* bias = (const float*)d_in[2];
    float* out = (float*)d_out;
    hipLaunchKernelGGL(fused_kernel, dim3(BN / MROW), dim3(BLOCK), 0, stream,
                       x, W, bias, out);
}

// Round 5
// 65.710 us; speedup vs baseline: 1.0728x; 1.0728x over previous
//
#include <hip/hip_runtime.h>
#include <hip/hip_bf16.h>
#include <math.h>

// Problem constants (B,U,D) = (4096, 256, 128)
#define BN 4096
#define UN 256
#define DN 128
#define MROW 16        // batch rows per block-tile (one M=16 MFMA tile)
#define BLOCK 1024     // 16 waves: wave w owns u-tile w
#define LSTRIDE 260    // logits row stride; 260 % 32 == 4 -> 2-way banks (free)

typedef __attribute__((ext_vector_type(8))) short short8x;   // 8 bf16
typedef __attribute__((ext_vector_type(4))) float float4x;   // MFMA C/D

// d_ws layout (bytes):
//   Wp   [0,       65536)   bf16 W, MFMA-fragment order: chunk = (u>>4)*256 + ks*64 + q*16 + (u&15)
//   Bp   [65536,  131072)   bf16 bias, same order
//   S    [131072, 135168)   float4[256] per-u: (nb2, bw, a_norm, scale) -- exact f32
//   Xp   [135168, 1183744)  bf16 x, fragment order: chunk = tile*256 + ks*64 + q*16 + r
//   NV2  [1183744, 1200128) float[4096] exact ||x_b||^2

__device__ inline uint pack2bf(float a, float b) {
    __hip_bfloat16 ha = __float2bfloat16(a);
    __hip_bfloat16 hb = __float2bfloat16(b);
    return (uint)(*(ushort*)&ha) | ((uint)(*(ushort*)&hb) << 16);
}

// ---- prep 1: W/bias -> bf16 fragment layout + per-u epilogue constants ----
__global__ __launch_bounds__(64) void prep_wb(
    const float* __restrict__ W, const float* __restrict__ bias,
    ushort* __restrict__ Wp, ushort* __restrict__ Bp, float4* __restrict__ S)
{
    const int u = blockIdx.x;
    const int l = threadIdx.x;            // 64 lanes, 2 floats each
    const float2 w2 = ((const float2*)(W    + (size_t)u * DN))[l];
    const float2 b2 = ((const float2*)(bias + (size_t)u * DN))[l];
    float nb2 = b2.x*b2.x + b2.y*b2.y;
    float bw  = b2.x*w2.x + b2.y*w2.y;
    float wn2 = w2.x*w2.x + w2.y*w2.y;
    #pragma unroll
    for (int off = 32; off; off >>= 1) {
        nb2 += __shfl_xor(nb2, off);
        bw  += __shfl_xor(bw , off);
        wn2 += __shfl_xor(wn2, off);
    }
    const int d  = 2 * l;
    const int ks = d >> 5, q = (d & 31) >> 3, j = d & 7;
    const int chunk = ((u >> 4) * 256) + ks * 64 + q * 16 + (u & 15);
    ((uint*)Wp)[chunk * 4 + (j >> 1)] = pack2bf(w2.x, w2.y);
    ((uint*)Bp)[chunk * 4 + (j >> 1)] = pack2bf(b2.x, b2.y);
    if (l == 0) {
        const float one_m  = 1.0f - nb2;
        const float a_norm = fabsf(one_m) * sqrtf(wn2);
        const float scale  = (2.0f / one_m) * a_norm;
        S[u] = make_float4(nb2, bw, a_norm, scale);
    }
}

// ---- prep 2: x -> bf16 fragment layout + exact nv2 ----
__global__ __launch_bounds__(256) void prep_x(
    const float* __restrict__ x, ushort* __restrict__ Xp, float* __restrict__ NV2)
{
    const int tile = blockIdx.x;
    const int h  = threadIdx.x;
    const int r  = h >> 4;          // row within tile
    const int hc = h & 15;          // 8-float chunk within row
    const float4* xp4 = (const float4*)(x + (size_t)(tile * MROW + r) * DN + hc * 8);
    const float4 a = xp4[0], b = xp4[1];
    float sq = a.x*a.x + a.y*a.y + a.z*a.z + a.w*a.w
             + b.x*b.x + b.y*b.y + b.z*b.z + b.w*b.w;
    uint4 p;
    p.x = pack2bf(a.x, a.y);  p.y = pack2bf(a.z, a.w);
    p.z = pack2bf(b.x, b.y);  p.w = pack2bf(b.z, b.w);
    const int ks = hc >> 2, q = hc & 3;
    ((uint4*)Xp)[tile * 256 + ks * 64 + q * 16 + r] = p;
    #pragma unroll
    for (int off = 1; off < 16; off <<= 1) sq += __shfl_xor(sq, off);
    if (hc == 0) NV2[tile * MROW + r] = sq;
}

// ---- main: fully-coalesced fragment loads + MFMA + epilogue + softmax ----
__global__ __launch_bounds__(BLOCK, 4) void main_kernel(
    const ushort* __restrict__ Xp, const ushort* __restrict__ Wp,
    const ushort* __restrict__ Bp, const float4* __restrict__ S,
    const float* __restrict__ NV2, float* __restrict__ out)
{
    __shared__ float logits[MROW][LSTRIDE];   // ~16.6 KB

    const int t    = threadIdx.x;
    const int lane = t & 63;
    const int wave = t >> 6;          // u-tile
    const int m16  = lane & 15;
    const int q    = lane >> 4;
    const int blk  = blockIdx.x;
    const int b0   = blk * MROW;
    const int u    = wave * 16 + m16;

    // fragment loads: base + lane*16B -> one 1KB transaction per instruction
    const short8x* xc = (const short8x*)Xp + blk  * 256 + lane;
    const short8x* wc = (const short8x*)Wp + wave * 256 + lane;
    const short8x* bc = (const short8x*)Bp + wave * 256 + lane;
    short8x af[4], wf[4], bf[4];
    #pragma unroll
    for (int ks = 0; ks < 4; ++ks) {
        af[ks] = xc[ks * 64];
        wf[ks] = wc[ks * 64];
        bf[ks] = bc[ks * 64];
    }
    const float4 sc  = S[u];                              // per-u constants
    const float4 nv4 = ((const float4*)(NV2 + b0))[q];    // rows q*4..q*4+3

    float4x accW = {0.f, 0.f, 0.f, 0.f};
    float4x accB = {0.f, 0.f, 0.f, 0.f};
    #pragma unroll
    for (int ks = 0; ks < 4; ++ks) {
        accW = __builtin_amdgcn_mfma_f32_16x16x32_bf16(af[ks], wf[ks], accW, 0, 0, 0);
        accB = __builtin_amdgcn_mfma_f32_16x16x32_bf16(af[ks], bf[ks], accB, 0, 0, 0);
    }

    // epilogue: C layout col = m16 (u), row = q*4+rg
    const float nb2 = sc.x, bw = sc.y, a_norm = sc.z, scale = sc.w;
    const float one_m = 1.0f - nb2;
    #pragma unroll
    for (int rg = 0; rg < 4; ++rg) {
        const float nv2  = ((const float*)&nv4)[rg];
        const float dot1 = accW[rg];
        const float xy   = -accB[rg];
        const float dd   = 1.0f + 2.0f * xy + nb2 * nv2;
        const float inv_dd = __builtin_amdgcn_rcpf(dd);
        const float alpha  = (1.0f + 2.0f * xy + nv2) * inv_dd;
        const float beta   = one_m * inv_dd;
        const float num = 2.0f * one_m * (beta * dot1 - alpha * bw);
        const float mm  = alpha * alpha * nb2 + 2.0f * alpha * beta * xy
                        + beta * beta * nv2;
        const float den = (1.0f - mm) * a_norm;
        const float z   = num * __builtin_amdgcn_rcpf(den);
        const float s   = sqrtf(fmaf(z, z, 1.0f));
        logits[q * 4 + rg][u] = scale * copysignf(__logf(fabsf(z) + s), z);
    }
    __syncthreads();

    // softmax: wave w handles row w, float4 I/O
    {
        const int r = wave;
        const float4 v = *(const float4*)&logits[r][lane * 4];
        float mx = fmaxf(fmaxf(v.x, v.y), fmaxf(v.z, v.w));
        #pragma unroll
        for (int off = 32; off; off >>= 1) mx = fmaxf(mx, __shfl_xor(mx, off));
        float4 e;
        e.x = __expf(v.x - mx);  e.y = __expf(v.y - mx);
        e.z = __expf(v.z - mx);  e.w = __expf(v.w - mx);
        float s = e.x + e.y + e.z + e.w;
        #pragma unroll
        for (int off = 32; off; off >>= 1) s += __shfl_xor(s, off);
        const float inv = __builtin_amdgcn_rcpf(s);
        e.x *= inv;  e.y *= inv;  e.z *= inv;  e.w *= inv;
        ((float4*)(out + (size_t)(b0 + r) * UN))[lane] = e;
    }
}

extern "C" void kernel_launch(void* const* d_in, const int* in_sizes, int n_in,
                              void* d_out, int out_size, void* d_ws, size_t ws_size,
                              hipStream_t stream) {
    const float* x    = (const float*)d_in[0];
    const float* W    = (const float*)d_in[1];
    const float* bias = (const float*)d_in[2];
    float* out = (float*)d_out;

    char* ws = (char*)d_ws;
    ushort* Wp  = (ushort*)(ws);
    ushort* Bp  = (ushort*)(ws + 65536);
    float4* S   = (float4*)(ws + 131072);
    ushort* Xp  = (ushort*)(ws + 135168);
    float*  NV2 = (float*) (ws + 1183744);

    hipLaunchKernelGGL(prep_wb, dim3(UN), dim3(64), 0, stream, W, bias, Wp, Bp, S);
    hipLaunchKernelGGL(prep_x, dim3(BN / MROW), dim3(256), 0, stream, x, Xp, NV2);
    hipLaunchKernelGGL(main_kernel, dim3(BN / MROW), dim3(BLOCK), 0, stream,
                       Xp, Wp, Bp, S, NV2, out);
}

// Round 6
// 64.183 us; speedup vs baseline: 1.0983x; 1.0238x over previous
//
#include <hip/hip_runtime.h>
#include <hip/hip_bf16.h>
#include <math.h>

// Problem constants (B,U,D) = (4096, 256, 128)
#define BN 4096
#define UN 256
#define DN 128
#define MROW 16        // batch rows per block (one M=16 MFMA tile)
#define BLOCK 1024     // 16 waves: wave w owns u-tile w
#define LSTRIDE 260    // logits row stride; 260 % 32 == 4 -> 2-way banks (free)

typedef __attribute__((ext_vector_type(8))) short short8x;   // 8 bf16
typedef __attribute__((ext_vector_type(4))) float float4x;   // MFMA C/D

// d_ws layout (bytes):
//   Wp [0,      65536)  bf16 W,   fragment order: chunk = (u>>4)*256 + ks*64 + q*16 + (u&15)
//   Bp [65536, 131072)  bf16 bias, same order
//   S  [131072,135168)  float4[256] per-u: (nb2, bw, a_norm, scale) -- exact f32

__device__ inline uint pack2bf(float a, float b) {
    __hip_bfloat16 ha = __float2bfloat16(a);
    __hip_bfloat16 hb = __float2bfloat16(b);
    return (uint)(*(ushort*)&ha) | ((uint)(*(ushort*)&hb) << 16);
}

// ---- prep: W/bias -> bf16 fragment layout + per-u epilogue constants ----
__global__ __launch_bounds__(64) void prep_wb(
    const float* __restrict__ W, const float* __restrict__ bias,
    ushort* __restrict__ Wp, ushort* __restrict__ Bp, float4* __restrict__ S)
{
    const int u = blockIdx.x;
    const int l = threadIdx.x;            // 64 lanes, 2 floats each
    const float2 w2 = ((const float2*)(W    + (size_t)u * DN))[l];
    const float2 b2 = ((const float2*)(bias + (size_t)u * DN))[l];
    float nb2 = b2.x*b2.x + b2.y*b2.y;
    float bw  = b2.x*w2.x + b2.y*w2.y;
    float wn2 = w2.x*w2.x + w2.y*w2.y;
    #pragma unroll
    for (int off = 32; off; off >>= 1) {
        nb2 += __shfl_xor(nb2, off);
        bw  += __shfl_xor(bw , off);
        wn2 += __shfl_xor(wn2, off);
    }
    const int d  = 2 * l;
    const int ks = d >> 5, q = (d & 31) >> 3, j = d & 7;
    const int chunk = ((u >> 4) * 256) + ks * 64 + q * 16 + (u & 15);
    ((uint*)Wp)[chunk * 4 + (j >> 1)] = pack2bf(w2.x, w2.y);
    ((uint*)Bp)[chunk * 4 + (j >> 1)] = pack2bf(b2.x, b2.y);
    if (l == 0) {
        const float one_m  = 1.0f - nb2;
        const float a_norm = fabsf(one_m) * sqrtf(wn2);
        const float scale  = (2.0f / one_m) * a_norm;
        S[u] = make_float4(nb2, bw, a_norm, scale);
    }
}

// ---- main: in-kernel x staging + MFMA + epilogue + softmax ----
__global__ __launch_bounds__(BLOCK, 4) void main_kernel(
    const float* __restrict__ x,
    const ushort* __restrict__ Wp, const ushort* __restrict__ Bp,
    const float4* __restrict__ S, float* __restrict__ out)
{
    __shared__ __align__(16) uint XL[MROW * DN / 2];   // 4 KB, bf16 fragment order
    __shared__ float nv2_lds[MROW];
    __shared__ float logits[MROW][LSTRIDE];            // ~16.6 KB

    const int t    = threadIdx.x;
    const int lane = t & 63;
    const int wave = t >> 6;          // u-tile index; also x-row during staging
    const int m16  = lane & 15;
    const int q    = lane >> 4;
    const int b0   = blockIdx.x * MROW;
    const int u    = wave * 16 + m16;

    // ---- phase A: stage x tile. wave w loads row w (64 lanes x float2,
    //      512B contiguous per wave), packs bf16 into fragment-order LDS.
    {
        const int d0 = lane * 2;
        const float2 v = *(const float2*)(x + (size_t)(b0 + wave) * DN + d0);
        float sq = fmaf(v.x, v.x, v.y * v.y);
        #pragma unroll
        for (int off = 32; off; off >>= 1) sq += __shfl_xor(sq, off);
        if (lane == 0) nv2_lds[wave] = sq;          // exact f32 ||x_row||^2
        const int ks = d0 >> 5, qq = (d0 & 31) >> 3, j = d0 & 7;
        XL[(ks * 64 + qq * 16 + wave) * 4 + (j >> 1)] = pack2bf(v.x, v.y);
    }

    // ---- W/bias fragment loads (global, L2-hot): base + lane*16B, coalesced
    const short8x* wc = (const short8x*)Wp + wave * 256 + lane;
    const short8x* bc = (const short8x*)Bp + wave * 256 + lane;
    short8x wf[4], bf[4];
    #pragma unroll
    for (int ks = 0; ks < 4; ++ks) {
        wf[ks] = wc[ks * 64];
        bf[ks] = bc[ks * 64];
    }
    const float4 sc = S[u];                         // per-u epilogue constants

    __syncthreads();

    // ---- A-fragments from LDS + MFMA
    const float4 nv4 = ((const float4*)nv2_lds)[q]; // rows q*4..q*4+3
    float4x accW = {0.f, 0.f, 0.f, 0.f};
    float4x accB = {0.f, 0.f, 0.f, 0.f};
    #pragma unroll
    for (int ks = 0; ks < 4; ++ks) {
        const short8x af = *(const short8x*)&XL[(ks * 64 + lane) * 4];
        accW = __builtin_amdgcn_mfma_f32_16x16x32_bf16(af, wf[ks], accW, 0, 0, 0);
        accB = __builtin_amdgcn_mfma_f32_16x16x32_bf16(af, bf[ks], accB, 0, 0, 0);
    }

    // ---- epilogue: C layout col = m16 (u), row = q*4+rg
    const float nb2 = sc.x, bw = sc.y, a_norm = sc.z, scale = sc.w;
    const float one_m = 1.0f - nb2;
    #pragma unroll
    for (int rg = 0; rg < 4; ++rg) {
        const float nv2  = ((const float*)&nv4)[rg];
        const float dot1 = accW[rg];
        const float xy   = -accB[rg];
        const float dd   = 1.0f + 2.0f * xy + nb2 * nv2;
        const float inv_dd = __builtin_amdgcn_rcpf(dd);
        const float alpha  = (1.0f + 2.0f * xy + nv2) * inv_dd;
        const float beta   = one_m * inv_dd;
        const float num = 2.0f * one_m * (beta * dot1 - alpha * bw);
        const float mm  = alpha * alpha * nb2 + 2.0f * alpha * beta * xy
                        + beta * beta * nv2;
        const float den = (1.0f - mm) * a_norm;
        const float z   = num * __builtin_amdgcn_rcpf(den);
        const float s   = sqrtf(fmaf(z, z, 1.0f));
        logits[q * 4 + rg][u] = scale * copysignf(__logf(fabsf(z) + s), z);
    }
    __syncthreads();

    // ---- softmax: wave w handles row w, float4 I/O
    {
        const float4 v = *(const float4*)&logits[wave][lane * 4];
        float mx = fmaxf(fmaxf(v.x, v.y), fmaxf(v.z, v.w));
        #pragma unroll
        for (int off = 32; off; off >>= 1) mx = fmaxf(mx, __shfl_xor(mx, off));
        float4 e;
        e.x = __expf(v.x - mx);  e.y = __expf(v.y - mx);
        e.z = __expf(v.z - mx);  e.w = __expf(v.w - mx);
        float s = e.x + e.y + e.z + e.w;
        #pragma unroll
        for (int off = 32; off; off >>= 1) s += __shfl_xor(s, off);
        const float inv = __builtin_amdgcn_rcpf(s);
        e.x *= inv;  e.y *= inv;  e.z *= inv;  e.w *= inv;
        ((float4*)(out + (size_t)(b0 + wave) * UN))[lane] = e;
    }
}

extern "C" void kernel_launch(void* const* d_in, const int* in_sizes, int n_in,
                              void* d_out, int out_size, void* d_ws, size_t ws_size,
                              hipStream_t stream) {
    const float* x    = (const float*)d_in[0];
    const float* W    = (const float*)d_in[1];
    const float* bias = (const float*)d_in[2];
    float* out = (float*)d_out;

    char* ws = (char*)d_ws;
    ushort* Wp = (ushort*)(ws);
    ushort* Bp = (ushort*)(ws + 65536);
    float4* S  = (float4*)(ws + 131072);

    hipLaunchKernelGGL(prep_wb, dim3(UN), dim3(64), 0, stream, W, bias, Wp, Bp, S);
    hipLaunchKernelGGL(main_kernel, dim3(BN / MROW), dim3(BLOCK), 0, stream,
                       x, Wp, Bp, S, out);
}

// Round 7
// 63.463 us; speedup vs baseline: 1.1108x; 1.0113x over previous
//
#include <hip/hip_runtime.h>
#include <hip/hip_bf16.h>
#include <math.h>

// Problem constants (B,U,D) = (4096, 256, 128)
#define BN 4096
#define UN 256
#define DN 128
#define MROW 16        // batch rows per block (one M=16 MFMA tile)
#define BLOCK 1024     // 16 waves: wave w owns u-tile w
#define LSTRIDE 260    // logits row stride; 260 % 32 == 4 -> 2-way banks (free)

typedef __attribute__((ext_vector_type(8))) short short8x;   // 8 bf16
typedef __attribute__((ext_vector_type(4))) float float4x;   // MFMA C/D

// d_ws layout (bytes):
//   Wp [0,      65536)  bf16 W,   fragment order: chunk = (u>>4)*256 + ks*64 + q*16 + (u&15)
//   Bp [65536, 131072)  bf16 bias, same order
//   S  [131072,135168)  float4[256] per-u: (nb2, bw, a_norm, scale) -- exact f32

__device__ inline uint pack2bf(float a, float b) {
    __hip_bfloat16 ha = __float2bfloat16(a);
    __hip_bfloat16 hb = __float2bfloat16(b);
    return (uint)(*(ushort*)&ha) | ((uint)(*(ushort*)&hb) << 16);
}

// ---- prep: W/bias -> bf16 fragment layout + per-u epilogue constants ----
// 16 blocks x 1024 threads: wave w of block b handles u = b*16 + w.
__global__ __launch_bounds__(1024) void prep_wb(
    const float* __restrict__ W, const float* __restrict__ bias,
    ushort* __restrict__ Wp, ushort* __restrict__ Bp, float4* __restrict__ S)
{
    const int u = blockIdx.x * 16 + (threadIdx.x >> 6);
    const int l = threadIdx.x & 63;       // 64 lanes, 2 floats each
    const float2 w2 = ((const float2*)(W    + (size_t)u * DN))[l];
    const float2 b2 = ((const float2*)(bias + (size_t)u * DN))[l];
    float nb2 = b2.x*b2.x + b2.y*b2.y;
    float bw  = b2.x*w2.x + b2.y*w2.y;
    float wn2 = w2.x*w2.x + w2.y*w2.y;
    #pragma unroll
    for (int off = 32; off; off >>= 1) {
        nb2 += __shfl_xor(nb2, off);
        bw  += __shfl_xor(bw , off);
        wn2 += __shfl_xor(wn2, off);
    }
    const int d  = 2 * l;
    const int ks = d >> 5, q = (d & 31) >> 3, j = d & 7;
    const int chunk = ((u >> 4) * 256) + ks * 64 + q * 16 + (u & 15);
    ((uint*)Wp)[chunk * 4 + (j >> 1)] = pack2bf(w2.x, w2.y);
    ((uint*)Bp)[chunk * 4 + (j >> 1)] = pack2bf(b2.x, b2.y);
    if (l == 0) {
        const float one_m  = 1.0f - nb2;
        const float a_norm = fabsf(one_m) * sqrtf(wn2);
        const float scale  = (2.0f / one_m) * a_norm;
        S[u] = make_float4(nb2, bw, a_norm, scale);
    }
}

// ---- main: in-kernel x staging + MFMA + epilogue + softmax ----
__global__ __launch_bounds__(BLOCK, 4) void main_kernel(
    const float* __restrict__ x,
    const ushort* __restrict__ Wp, const ushort* __restrict__ Bp,
    const float4* __restrict__ S, float* __restrict__ out)
{
    __shared__ __align__(16) uint XL[MROW * DN / 2];   // 4 KB, bf16 fragment order
    __shared__ float nv2_lds[MROW];
    __shared__ float logits[MROW][LSTRIDE];            // ~16.6 KB

    const int t    = threadIdx.x;
    const int lane = t & 63;
    const int wave = t >> 6;          // u-tile index; also x-row during staging
    const int m16  = lane & 15;
    const int q    = lane >> 4;
    const int b0   = blockIdx.x * MROW;
    const int u    = wave * 16 + m16;

    // ---- issue W/bias/S global loads FIRST (no LDS dependency) so their
    //      latency overlaps the x staging phase below.
    const short8x* wc = (const short8x*)Wp + wave * 256 + lane;
    const short8x* bc = (const short8x*)Bp + wave * 256 + lane;
    short8x wf[4], bf[4];
    #pragma unroll
    for (int ks = 0; ks < 4; ++ks) {
        wf[ks] = wc[ks * 64];
        bf[ks] = bc[ks * 64];
    }
    const float4 sc = S[u];                         // per-u epilogue constants

    // ---- phase A: stage x tile. wave w loads row w (64 lanes x float2,
    //      512B contiguous per wave), packs bf16 into fragment-order LDS.
    {
        const int d0 = lane * 2;
        const float2 v = *(const float2*)(x + (size_t)(b0 + wave) * DN + d0);
        float sq = fmaf(v.x, v.x, v.y * v.y);
        #pragma unroll
        for (int off = 32; off; off >>= 1) sq += __shfl_xor(sq, off);
        if (lane == 0) nv2_lds[wave] = sq;          // exact f32 ||x_row||^2
        const int ks = d0 >> 5, qq = (d0 & 31) >> 3, j = d0 & 7;
        XL[(ks * 64 + qq * 16 + wave) * 4 + (j >> 1)] = pack2bf(v.x, v.y);
    }

    __syncthreads();

    // ---- A-fragments from LDS + MFMA
    const float4 nv4 = ((const float4*)nv2_lds)[q]; // rows q*4..q*4+3
    float4x accW = {0.f, 0.f, 0.f, 0.f};
    float4x accB = {0.f, 0.f, 0.f, 0.f};
    #pragma unroll
    for (int ks = 0; ks < 4; ++ks) {
        const short8x af = *(const short8x*)&XL[(ks * 64 + lane) * 4];
        accW = __builtin_amdgcn_mfma_f32_16x16x32_bf16(af, wf[ks], accW, 0, 0, 0);
        accB = __builtin_amdgcn_mfma_f32_16x16x32_bf16(af, bf[ks], accB, 0, 0, 0);
    }

    // ---- epilogue: C layout col = m16 (u), row = q*4+rg
    const float nb2 = sc.x, bw = sc.y, a_norm = sc.z, scale = sc.w;
    const float one_m = 1.0f - nb2;
    #pragma unroll
    for (int rg = 0; rg < 4; ++rg) {
        const float nv2  = ((const float*)&nv4)[rg];
        const float dot1 = accW[rg];
        const float xy   = -accB[rg];
        const float dd   = 1.0f + 2.0f * xy + nb2 * nv2;
        const float inv_dd = __builtin_amdgcn_rcpf(dd);
        const float alpha  = (1.0f + 2.0f * xy + nv2) * inv_dd;
        const float beta   = one_m * inv_dd;
        const float num = 2.0f * one_m * (beta * dot1 - alpha * bw);
        const float mm  = alpha * alpha * nb2 + 2.0f * alpha * beta * xy
                        + beta * beta * nv2;
        const float den = (1.0f - mm) * a_norm;
        const float z   = num * __builtin_amdgcn_rcpf(den);
        const float s   = sqrtf(fmaf(z, z, 1.0f));
        logits[q * 4 + rg][u] = scale * copysignf(__logf(fabsf(z) + s), z);
    }
    __syncthreads();

    // ---- softmax: wave w handles row w, float4 I/O
    {
        const float4 v = *(const float4*)&logits[wave][lane * 4];
        float mx = fmaxf(fmaxf(v.x, v.y), fmaxf(v.z, v.w));
        #pragma unroll
        for (int off = 32; off; off >>= 1) mx = fmaxf(mx, __shfl_xor(mx, off));
        float4 e;
        e.x = __expf(v.x - mx);  e.y = __expf(v.y - mx);
        e.z = __expf(v.z - mx);  e.w = __expf(v.w - mx);
        float s = e.x + e.y + e.z + e.w;
        #pragma unroll
        for (int off = 32; off; off >>= 1) s += __shfl_xor(s, off);
        const float inv = __builtin_amdgcn_rcpf(s);
        e.x *= inv;  e.y *= inv;  e.z *= inv;  e.w *= inv;
        ((float4*)(out + (size_t)(b0 + wave) * UN))[lane] = e;
    }
}

extern "C" void kernel_launch(void* const* d_in, const int* in_sizes, int n_in,
                              void* d_out, int out_size, void* d_ws, size_t ws_size,
                              hipStream_t stream) {
    const float* x    = (const float*)d_in[0];
    const float* W    = (const float*)d_in[1];
    const float* bias = (const float*)d_in[2];
    float* out = (float*)d_out;

    char* ws = (char*)d_ws;
    ushort* Wp = (ushort*)(ws);
    ushort* Bp = (ushort*)(ws + 65536);
    float4* S  = (float4*)(ws + 131072);

    hipLaunchKernelGGL(prep_wb, dim3(UN / 16), dim3(1024), 0, stream, W, bias, Wp, Bp, S);
    hipLaunchKernelGGL(main_kernel, dim3(BN / MROW), dim3(BLOCK), 0, stream,
                       x, Wp, Bp, S, out);
}